// Round 6
// baseline (307.930 us; speedup 1.0000x reference)
//
#include <hip/hip_runtime.h>
#include <hip/hip_bf16.h>

typedef __bf16 bf16;
typedef __attribute__((ext_vector_type(4))) __bf16 bf16x4;
typedef __attribute__((ext_vector_type(8))) __bf16 bf16x8;
typedef __attribute__((ext_vector_type(4))) float f32x4;
typedef __attribute__((ext_vector_type(16))) float f32x16;
typedef __attribute__((ext_vector_type(2))) unsigned u32x2;
typedef __attribute__((ext_vector_type(4))) unsigned u32x4;

#define B_ 4
#define T_ 2048
#define C_ 1024
#define H_ 16
#define D_ 64
#define BT_ (B_*T_)

#define NEG_INF (-__builtin_inff())

__device__ __forceinline__ void gld16(const void* g, void* l) {
  __builtin_amdgcn_global_load_lds(
      (const __attribute__((address_space(1))) void*)g,
      (__attribute__((address_space(3))) void*)l, 16, 0, 0);
}

__device__ __forceinline__ unsigned cvtpk(float lo, float hi) {
  unsigned r;
  asm("v_cvt_pk_bf16_f32 %0, %1, %2" : "=v"(r) : "v"(lo), "v"(hi));
  return r;
}

// ---------------- preprocessing ----------------

__global__ void cast_x(const float* __restrict__ in, bf16* __restrict__ out) {
  int i = blockIdx.x * 256 + threadIdx.x;
  f32x4 v = reinterpret_cast<const f32x4*>(in)[i];
  bf16x4 o;
  o[0] = (bf16)v[0]; o[1] = (bf16)v[1]; o[2] = (bf16)v[2]; o[3] = (bf16)v[3];
  reinterpret_cast<bf16x4*>(out)[i] = o;
}

// in [R][Cc] fp32  ->  out [Cc][R] bf16
__global__ void transpose_cast(const float* __restrict__ in, bf16* __restrict__ out,
                               int R, int Cc) {
  __shared__ float tile[32][33];
  int tx = threadIdx.x, ty = threadIdx.y;
  int x  = blockIdx.x * 32 + tx;
  int y0 = blockIdx.y * 32;
#pragma unroll
  for (int j = 0; j < 32; j += 8)
    tile[ty + j][tx] = in[(size_t)(y0 + ty + j) * Cc + x];
  __syncthreads();
  int ox  = y0 + tx;
  int oy0 = blockIdx.x * 32;
#pragma unroll
  for (int j = 0; j < 32; j += 8)
    out[(size_t)(oy0 + ty + j) * R + ox] = (bf16)tile[tx][ty + j];
}

// ---------------- GEMM: C[M][N] = A[M][K] @ Bt[N][K]^T + bias ----------------
// 128x256 tile, 8 waves (2M x 4N, 64x64 each), BK=32.
// 3-buffer depth-2 prefetch, counted vmcnt(3), ONE barrier per K-step.
// XCD-aware block swizzle (grids are multiples of 8).

template<int EPI>
__global__ __launch_bounds__(512, 4)
void gemm_bt(const bf16* __restrict__ A, const bf16* __restrict__ Bt,
             const float* __restrict__ bias, float* __restrict__ outF,
             bf16* __restrict__ qb, bf16* __restrict__ kb, bf16* __restrict__ vb,
             int M, int N, int K) {
  __shared__ alignas(16) bf16 As[3][128 * 32];
  __shared__ alignas(16) bf16 Bs[3][256 * 32];
  const int tid = threadIdx.x;
  const int lane = tid & 63, wid = tid >> 6;
  const int wm = wid >> 2, wn = wid & 3;           // 2x4 waves, 64x64 each
  const int lr = lane & 15, lg = lane >> 4;

  const int nbx = gridDim.x;
  const int nwg = nbx * gridDim.y;
  const int bid = blockIdx.y * nbx + blockIdx.x;
  const int swz = (bid & 7) * (nwg >> 3) + (bid >> 3);   // XCD swizzle
  const int m0 = (swz / nbx) * 128, n0 = (swz % nbx) * 256;

  f32x4 acc[4][4] = {};

#define GSTAGE(BF, KT) do {                                                    \
    int k0_ = (KT) << 5;                                                       \
    { int row_ = tid >> 2, ke_ = (tid & 3) << 3;                               \
      gld16(A + (size_t)(m0 + row_) * K + k0_ + ke_, As[BF] + tid * 8); }      \
    _Pragma("unroll")                                                          \
    for (int j_ = 0; j_ < 2; ++j_) {                                           \
      int s_ = j_ * 512 + tid;                                                 \
      int row_ = s_ >> 2, ke_ = (s_ & 3) << 3;                                 \
      gld16(Bt + (size_t)(n0 + row_) * K + k0_ + ke_, Bs[BF] + s_ * 8);        \
    }                                                                          \
  } while (0)

  const int ktiles = K >> 5;
  GSTAGE(0, 0);
  GSTAGE(1, 1);
  for (int kt = 0; kt < ktiles; ++kt) {
    if (kt + 1 < ktiles) asm volatile("s_waitcnt vmcnt(3)" ::: "memory");
    else                 asm volatile("s_waitcnt vmcnt(0)" ::: "memory");
    __builtin_amdgcn_s_barrier();
    asm volatile("" ::: "memory");
    if (kt + 2 < ktiles) GSTAGE((kt + 2) % 3, kt + 2);

    const bf16* Ac = As[kt % 3];
    const bf16* Bc = Bs[kt % 3];
    bf16x8 af[4], bfr[4];
#pragma unroll
    for (int i = 0; i < 4; i++)
      af[i]  = *(const bf16x8*)(Ac + ((wm * 64 + i * 16 + lr) << 5) + (lg << 3));
#pragma unroll
    for (int j = 0; j < 4; j++)
      bfr[j] = *(const bf16x8*)(Bc + ((wn * 64 + j * 16 + lr) << 5) + (lg << 3));
#pragma unroll
    for (int i = 0; i < 4; i++)
#pragma unroll
      for (int j = 0; j < 4; j++)
        acc[i][j] = __builtin_amdgcn_mfma_f32_16x16x32_bf16(af[i], bfr[j], acc[i][j], 0, 0, 0);
  }
#undef GSTAGE

  if (EPI == 1) {
#pragma unroll
    for (int i = 0; i < 4; i++) {
      int row = m0 + wm * 64 + i * 16 + lg * 4;
#pragma unroll
      for (int j = 0; j < 4; j++) {
        int col = n0 + wn * 64 + j * 16 + lr;
        float bv = bias[col];
#pragma unroll
        for (int r = 0; r < 4; r++)
          outF[(size_t)(row + r) * N + col] = acc[i][j][r] + bv;
      }
    }
  } else {
    const int sect = n0 >> 10;                     // 0=q 1=k 2=v (uniform per block)
#pragma unroll
    for (int i = 0; i < 4; i++) {
      int row = m0 + wm * 64 + i * 16 + lg * 4;
#pragma unroll
      for (int j = 0; j < 4; j++) {
        int col = n0 + wn * 64 + j * 16 + lr;
        float bv = bias[col];
        int cm = col & 1023;
        int h = cm >> 6, d = cm & 63;
#pragma unroll
        for (int r = 0; r < 4; r++) {
          float v = acc[i][j][r] + bv;
          int rt = row + r;
          int b = rt >> 11, t = rt & 2047;
          bf16 o = (bf16)v;
          size_t bh = (size_t)(b * H_ + h);
          if (sect == 0)      qb[(bh * T_ + t) * D_ + d] = o;   // [B,H,T,D]
          else if (sect == 1) kb[(bh * T_ + t) * D_ + d] = o;   // [B,H,T,D]
          else                vb[(bh * D_ + d) * T_ + t] = o;   // [B,H,D,T] (V^T)
        }
      }
    }
  }
}

// ---------------- flash attention (32x32 swapped-operand, in-register softmax) ----
// grid: (T/256, B*H); 256 threads = 4 waves, wave w owns 32 q rows.
// Work-balanced: block p handles qblk {NQ-1-p} then {p} -> 34 tiles/block flat.
// 3-buffer depth-2 prefetch, counted vmcnt(4) (T3/T4): load->wait gap = 2 tiles.

#if __has_builtin(__builtin_amdgcn_permlane32_swap)
#define PERMSWAP(A, B, LOW, HIW) do {                                           \
    auto _r = __builtin_amdgcn_permlane32_swap((unsigned)(A), (unsigned)(B),    \
                                               false, false);                   \
    __builtin_memcpy(&(LOW), &_r, 4);                                           \
    __builtin_memcpy(&(HIW), (const char*)&_r + 4, 4);                          \
  } while (0)
#else
#define PERMSWAP(A, B, LOW, HIW) do {                                           \
    unsigned _sb = (unsigned)__shfl_xor((int)(B), 32, 64);                      \
    unsigned _sa = (unsigned)__shfl_xor((int)(A), 32, 64);                      \
    (LOW) = hi ? _sb : (A);                                                     \
    (HIW) = hi ? (B) : _sa;                                                     \
  } while (0)
#endif

__global__ __launch_bounds__(256, 4)
void attn_fwd(const bf16* __restrict__ qg, const bf16* __restrict__ kg,
              const bf16* __restrict__ vg, bf16* __restrict__ yb) {
  __shared__ alignas(16) bf16 Ks[3][64 * 64];
  __shared__ alignas(16) bf16 Vs[3][64 * 64];   // V^T tile: [d][k_local]
  const int tid = threadIdx.x;
  const int lane = tid & 63, wid = tid >> 6;
  const int hi = lane >> 5, lq = lane & 31;
  const int xr = (lq & 7) << 4;
  const int bh = blockIdx.y;
  const int NQ = T_ / 128;

  const char* kbase = (const char*)(kg + (size_t)bh * T_ * D_);
  const char* vbase = (const char*)(vg + (size_t)bh * D_ * T_);
  const int b_ = bh >> 4, h = bh & 15;

#define STAGE(BF, TT) do {                                                     \
    _Pragma("unroll")                                                          \
    for (int j_ = 0; j_ < 2; ++j_) {                                           \
      int s_ = j_ * 256 + tid;                                                 \
      int row_ = s_ >> 3;                                                      \
      int scb_ = ((s_ & 7) << 4) ^ ((row_ & 7) << 4);                          \
      gld16(kbase + (size_t)((TT) * 64 + row_) * 128 + scb_,                   \
            (char*)Ks[BF] + s_ * 16);                                          \
      gld16(vbase + (size_t)row_ * (T_ * 2) + (TT) * 128 + scb_,               \
            (char*)Vs[BF] + s_ * 16);                                          \
    }                                                                          \
  } while (0)

  for (int ph = 0; ph < 2; ++ph) {
    const int qblk = ph ? (int)blockIdx.x : (NQ - 1 - (int)blockIdx.x);
    const int wq0 = qblk * 128 + wid * 32;
    const int qrow = wq0 + lq;
    const int nt = 2 * qblk + 2;

    if (ph) __builtin_amdgcn_s_barrier();   // all waves done reading LDS of ph0
    STAGE(0, 0);
    STAGE(1, 1);

    // Q B-fragments: lane holds q-col = qrow, d = 16s + 8hi + e
    const bf16* qptr = qg + ((size_t)bh * T_ + qrow) * D_ + hi * 8;
    bf16x8 qf[4];
#pragma unroll
    for (int s = 0; s < 4; s++) {
      qf[s] = *(const bf16x8*)(qptr + 16 * s);
      asm volatile("" : "+v"(qf[s]));
    }

    f32x16 o[2] = {};              // O^T: block db rows d=32db+crow, col q=lq
    float mrow = NEG_INF, lrow = 0.f;

    for (int t = 0; t < nt; ++t) {
      if (t + 1 < nt) asm volatile("s_waitcnt vmcnt(4)" ::: "memory");
      else            asm volatile("s_waitcnt vmcnt(0)" ::: "memory");
      __builtin_amdgcn_s_barrier();
      asm volatile("" ::: "memory");
      if (t + 2 < nt) STAGE((t + 2) % 3, t + 2);

      const char* Kc = (const char*)Ks[t % 3];
      const char* Vc = (const char*)Vs[t % 3];

      // S^T[k][q] for this wave's 32 q cols; 2 blocks of 32 k
      f32x16 S[2] = {};
      __builtin_amdgcn_s_setprio(1);
#pragma unroll
      for (int s = 0; s < 4; s++) {
#pragma unroll
        for (int b = 0; b < 2; b++) {
          bf16x8 kf = *(const bf16x8*)(Kc + (b * 32 + lq) * 128 +
                                       ((32 * s + 16 * hi) ^ xr));
          S[b] = __builtin_amdgcn_mfma_f32_32x32x16_bf16(kf, qf[s], S[b], 0, 0, 0);
        }
      }
      __builtin_amdgcn_s_setprio(0);

      // causal mask (raw-score domain)
      if (t >= nt - 2) {
#pragma unroll
        for (int b = 0; b < 2; b++)
#pragma unroll
          for (int r = 0; r < 16; r++) {
            int kgl = t * 64 + b * 32 + (r & 3) + 8 * (r >> 2) + 4 * hi;
            if (kgl > qrow) S[b][r] = NEG_INF;
          }
      }

      // online softmax, fully in-register (one cross-lane op per reduce)
      float tm = NEG_INF;
#pragma unroll
      for (int b = 0; b < 2; b++)
#pragma unroll
        for (int r = 0; r < 16; r++) tm = fmaxf(tm, S[b][r]);
      tm = fmaxf(tm, __shfl_xor(tm, 32, 64));

      float mn = fmaxf(mrow, 0.125f * tm);
      float alpha = __expf(mrow - mn);     // exp(-inf)=0 on first tile
      mrow = mn;
      float rs = 0.f;
#pragma unroll
      for (int b = 0; b < 2; b++)
#pragma unroll
        for (int r = 0; r < 16; r++) {
          float e = __expf(fmaf(S[b][r], 0.125f, -mn));
          S[b][r] = e;
          rs += e;
        }
      rs += __shfl_xor(rs, 32, 64);
      lrow = lrow * alpha + rs;
#pragma unroll
      for (int db = 0; db < 2; db++)
#pragma unroll
        for (int r = 0; r < 16; r++) o[db][r] *= alpha;

      // O^T += V^T * P^T ; P^T B-fragment built via cvt_pk + permlane32_swap
      __builtin_amdgcn_s_setprio(1);
#pragma unroll
      for (int ks = 0; ks < 4; ks++) {
        const int b = ks >> 1, hf = ks & 1;
        unsigned A0 = cvtpk(S[b][8 * hf + 0], S[b][8 * hf + 1]);
        unsigned A1 = cvtpk(S[b][8 * hf + 2], S[b][8 * hf + 3]);
        unsigned B0 = cvtpk(S[b][8 * hf + 4], S[b][8 * hf + 5]);
        unsigned B1 = cvtpk(S[b][8 * hf + 6], S[b][8 * hf + 7]);
        unsigned w0, w1, w2, w3;
        PERMSWAP(A0, B0, w0, w2);
        PERMSWAP(A1, B1, w1, w3);
        u32x4 wv = {w0, w1, w2, w3};
        bf16x8 pf = __builtin_bit_cast(bf16x8, wv);
#pragma unroll
        for (int db = 0; db < 2; db++) {
          bf16x8 vf = *(const bf16x8*)(Vc + (db * 32 + lq) * 128 +
                                       ((32 * ks + 16 * hi) ^ xr));
          o[db] = __builtin_amdgcn_mfma_f32_32x32x16_bf16(vf, pf, o[db], 0, 0, 0);
        }
      }
      __builtin_amdgcn_s_setprio(0);
    }

    // epilogue: O^T lane holds q=qrow col; d = 32db + 8rq + 4hi + rr
    float inv = 1.f / lrow;
    bf16* yrow = yb + ((size_t)(b_ * T_ + qrow)) * C_ + h * 64 + hi * 4;
#pragma unroll
    for (int db = 0; db < 2; db++)
#pragma unroll
      for (int rq = 0; rq < 4; rq++) {
        unsigned w0 = cvtpk(o[db][4 * rq + 0] * inv, o[db][4 * rq + 1] * inv);
        unsigned w1 = cvtpk(o[db][4 * rq + 2] * inv, o[db][4 * rq + 3] * inv);
        u32x2 wv = {w0, w1};
        *(u32x2*)(yrow + db * 32 + rq * 8) = wv;
      }
  }
#undef STAGE
}

// ---------------- launch ----------------

extern "C" void kernel_launch(void* const* d_in, const int* in_sizes, int n_in,
                              void* d_out, int out_size, void* d_ws, size_t ws_size,
                              hipStream_t stream) {
  (void)in_sizes; (void)n_in; (void)out_size; (void)ws_size;
  const float* x      = (const float*)d_in[0];
  const float* w_attn = (const float*)d_in[1];
  const float* b_attn = (const float*)d_in[2];
  const float* w_proj = (const float*)d_in[3];
  const float* b_proj = (const float*)d_in[4];
  float* out = (float*)d_out;

  char* ws = (char*)d_ws;
  bf16* x_bf = (bf16*)ws;  ws += (size_t)BT_ * C_ * 2;      // 16 MB
  bf16* wat  = (bf16*)ws;  ws += (size_t)3 * C_ * C_ * 2;   //  6 MB  [3C][C]
  bf16* wpt  = (bf16*)ws;  ws += (size_t)C_ * C_ * 2;       //  2 MB  [C][C]
  bf16* qbuf = (bf16*)ws;  ws += (size_t)BT_ * C_ * 2;      // 16 MB  [B,H,T,D]
  bf16* kbuf = (bf16*)ws;  ws += (size_t)BT_ * C_ * 2;      // 16 MB  [B,H,T,D]
  bf16* vbuf = (bf16*)ws;  ws += (size_t)BT_ * C_ * 2;      // 16 MB  [B,H,D,T]
  bf16* ybuf = (bf16*)ws;                                    // 16 MB  [B,T,C]

  cast_x<<<(BT_ * C_ / 4) / 256, 256, 0, stream>>>(x, x_bf);
  transpose_cast<<<dim3(3 * C_ / 32, C_ / 32), dim3(32, 8), 0, stream>>>(w_attn, wat, C_, 3 * C_);
  transpose_cast<<<dim3(C_ / 32, C_ / 32), dim3(32, 8), 0, stream>>>(w_proj, wpt, C_, C_);

  gemm_bt<0><<<dim3(3 * C_ / 256, BT_ / 128), 512, 0, stream>>>(
      x_bf, wat, b_attn, nullptr, qbuf, kbuf, vbuf, BT_, 3 * C_, C_);

  attn_fwd<<<dim3(T_ / 256, B_ * H_), 256, 0, stream>>>(qbuf, kbuf, vbuf, ybuf);

  gemm_bt<1><<<dim3(C_ / 256, BT_ / 128), 512, 0, stream>>>(
      ybuf, wpt, b_proj, out, nullptr, nullptr, nullptr, BT_, C_, C_);
}

// Round 7
// 288.972 us; speedup vs baseline: 1.0656x; 1.0656x over previous
//
#include <hip/hip_runtime.h>
#include <hip/hip_bf16.h>

typedef __bf16 bf16;
typedef __attribute__((ext_vector_type(4))) __bf16 bf16x4;
typedef __attribute__((ext_vector_type(8))) __bf16 bf16x8;
typedef __attribute__((ext_vector_type(4))) float f32x4;
typedef __attribute__((ext_vector_type(16))) float f32x16;
typedef __attribute__((ext_vector_type(2))) unsigned u32x2;
typedef __attribute__((ext_vector_type(4))) unsigned u32x4;

#define B_ 4
#define T_ 2048
#define C_ 1024
#define H_ 16
#define D_ 64
#define BT_ (B_*T_)

#define NEG_INF (-__builtin_inff())

__device__ __forceinline__ void gld16(const void* g, void* l) {
  __builtin_amdgcn_global_load_lds(
      (const __attribute__((address_space(1))) void*)g,
      (__attribute__((address_space(3))) void*)l, 16, 0, 0);
}

__device__ __forceinline__ unsigned cvtpk(float lo, float hi) {
  unsigned r;
  asm("v_cvt_pk_bf16_f32 %0, %1, %2" : "=v"(r) : "v"(lo), "v"(hi));
  return r;
}

// ---------------- preprocessing ----------------

__global__ void cast_x(const float* __restrict__ in, bf16* __restrict__ out) {
  int i = blockIdx.x * 256 + threadIdx.x;
  f32x4 v = reinterpret_cast<const f32x4*>(in)[i];
  bf16x4 o;
  o[0] = (bf16)v[0]; o[1] = (bf16)v[1]; o[2] = (bf16)v[2]; o[3] = (bf16)v[3];
  reinterpret_cast<bf16x4*>(out)[i] = o;
}

// in [R][Cc] fp32  ->  out [Cc][R] bf16
__global__ void transpose_cast(const float* __restrict__ in, bf16* __restrict__ out,
                               int R, int Cc) {
  __shared__ float tile[32][33];
  int tx = threadIdx.x, ty = threadIdx.y;
  int x  = blockIdx.x * 32 + tx;
  int y0 = blockIdx.y * 32;
#pragma unroll
  for (int j = 0; j < 32; j += 8)
    tile[ty + j][tx] = in[(size_t)(y0 + ty + j) * Cc + x];
  __syncthreads();
  int ox  = y0 + tx;
  int oy0 = blockIdx.x * 32;
#pragma unroll
  for (int j = 0; j < 32; j += 8)
    out[(size_t)(oy0 + ty + j) * R + ox] = (bf16)tile[tx][ty + j];
}

// ---------------- GEMM: C[M][N] = A[M][K] @ Bt[N][K]^T + bias ----------------
// 128x256 tile, 8 waves (2M x 4N, 64x64 each), BK=32.
// 3-buffer depth-2 prefetch, counted vmcnt(3), ONE barrier per K-step.
// T2 both-sides LDS swizzle: 16B slot ^= (row^(row>>2))&3  (2-way = free).
// Within-XCD m-minor order: B-panel L2-resident across 8 m-neighbors.

template<int EPI>
__global__ __launch_bounds__(512, 4)
void gemm_bt(const bf16* __restrict__ A, const bf16* __restrict__ Bt,
             const float* __restrict__ bias, float* __restrict__ outF,
             bf16* __restrict__ qb, bf16* __restrict__ kb, bf16* __restrict__ vb,
             int M, int N, int K) {
  __shared__ alignas(16) bf16 As[3][128 * 32];
  __shared__ alignas(16) bf16 Bs[3][256 * 32];
  const int tid = threadIdx.x;
  const int lane = tid & 63, wid = tid >> 6;
  const int wm = wid >> 2, wn = wid & 3;           // 2x4 waves, 64x64 each
  const int lr = lane & 15, lg = lane >> 4;
  const int fx = (lr ^ (lr >> 2)) & 3;             // read-side swizzle (row bits0-3 == lr)
  const int koff = (lg ^ fx) << 3;                 // element offset within 32-elem row

  // XCD-aware, m-minor within XCD: consecutive j share the B n-panel (L2 reuse)
  const int nbx = gridDim.x;
  const int bid = blockIdx.y * nbx + blockIdx.x;
  const int x = bid & 7, j = bid >> 3;
  const int mpx = gridDim.y >> 3;                  // m-tiles per XCD
  const int m0 = (x * mpx + j % mpx) * 128;
  const int n0 = (j / mpx) * 256;

  f32x4 acc[4][4] = {};

#define GSTAGE(BF, KT) do {                                                    \
    int k0_ = (KT) << 5;                                                       \
    { int row_ = tid >> 2, sl_ = tid & 3;                                      \
      int gs_ = sl_ ^ ((row_ ^ (row_ >> 2)) & 3);                              \
      gld16(A + (size_t)(m0 + row_) * K + k0_ + (gs_ << 3), As[BF] + tid * 8); }\
    _Pragma("unroll")                                                          \
    for (int j_ = 0; j_ < 2; ++j_) {                                           \
      int s_ = j_ * 512 + tid;                                                 \
      int row_ = s_ >> 2, sl_ = s_ & 3;                                        \
      int gs_ = sl_ ^ ((row_ ^ (row_ >> 2)) & 3);                              \
      gld16(Bt + (size_t)(n0 + row_) * K + k0_ + (gs_ << 3), Bs[BF] + s_ * 8); \
    }                                                                          \
  } while (0)

  const int ktiles = K >> 5;
  GSTAGE(0, 0);
  GSTAGE(1, 1);
  for (int kt = 0; kt < ktiles; ++kt) {
    if (kt + 1 < ktiles) asm volatile("s_waitcnt vmcnt(3)" ::: "memory");
    else                 asm volatile("s_waitcnt vmcnt(0)" ::: "memory");
    __builtin_amdgcn_s_barrier();
    asm volatile("" ::: "memory");
    if (kt + 2 < ktiles) GSTAGE((kt + 2) % 3, kt + 2);

    const bf16* Ac = As[kt % 3];
    const bf16* Bc = Bs[kt % 3];
    bf16x8 af[4], bfr[4];
#pragma unroll
    for (int i = 0; i < 4; i++)
      af[i]  = *(const bf16x8*)(Ac + ((wm * 64 + i * 16 + lr) << 5) + koff);
#pragma unroll
    for (int j2 = 0; j2 < 4; j2++)
      bfr[j2] = *(const bf16x8*)(Bc + ((wn * 64 + j2 * 16 + lr) << 5) + koff);
    __builtin_amdgcn_s_setprio(1);
#pragma unroll
    for (int i = 0; i < 4; i++)
#pragma unroll
      for (int j2 = 0; j2 < 4; j2++)
        acc[i][j2] = __builtin_amdgcn_mfma_f32_16x16x32_bf16(af[i], bfr[j2], acc[i][j2], 0, 0, 0);
    __builtin_amdgcn_s_setprio(0);
  }
#undef GSTAGE

  if (EPI == 1) {
#pragma unroll
    for (int i = 0; i < 4; i++) {
      int row = m0 + wm * 64 + i * 16 + lg * 4;
#pragma unroll
      for (int j2 = 0; j2 < 4; j2++) {
        int col = n0 + wn * 64 + j2 * 16 + lr;
        float bv = bias[col];
#pragma unroll
        for (int r = 0; r < 4; r++)
          outF[(size_t)(row + r) * N + col] = acc[i][j2][r] + bv;
      }
    }
  } else {
    const int sect = n0 >> 10;                     // 0=q 1=k 2=v (uniform per block)
#pragma unroll
    for (int i = 0; i < 4; i++) {
      int row = m0 + wm * 64 + i * 16 + lg * 4;
#pragma unroll
      for (int j2 = 0; j2 < 4; j2++) {
        int col = n0 + wn * 64 + j2 * 16 + lr;
        float bv = bias[col];
        int cm = col & 1023;
        int h = cm >> 6, d = cm & 63;
#pragma unroll
        for (int r = 0; r < 4; r++) {
          float v = acc[i][j2][r] + bv;
          int rt = row + r;
          int b = rt >> 11, t = rt & 2047;
          bf16 o = (bf16)v;
          size_t bh = (size_t)(b * H_ + h);
          if (sect == 0)      qb[(bh * T_ + t) * D_ + d] = o;   // [B,H,T,D]
          else if (sect == 1) kb[(bh * T_ + t) * D_ + d] = o;   // [B,H,T,D]
          else                vb[(bh * D_ + d) * T_ + t] = o;   // [B,H,D,T] (V^T)
        }
      }
    }
  }
}

// ---------------- flash attention (32x32 swapped-operand, in-register softmax) ----
// grid: (T/256, B*H); 256 threads = 4 waves, wave w owns 32 q rows.
// Work-balanced: block p handles qblk {NQ-1-p} then {p} -> 34 tiles/block flat.
// 3-buffer depth-2 prefetch, counted vmcnt(4) (T3/T4): load->wait gap = 2 tiles.

#if __has_builtin(__builtin_amdgcn_permlane32_swap)
#define PERMSWAP(A, B, LOW, HIW) do {                                           \
    auto _r = __builtin_amdgcn_permlane32_swap((unsigned)(A), (unsigned)(B),    \
                                               false, false);                   \
    __builtin_memcpy(&(LOW), &_r, 4);                                           \
    __builtin_memcpy(&(HIW), (const char*)&_r + 4, 4);                          \
  } while (0)
#else
#define PERMSWAP(A, B, LOW, HIW) do {                                           \
    unsigned _sb = (unsigned)__shfl_xor((int)(B), 32, 64);                      \
    unsigned _sa = (unsigned)__shfl_xor((int)(A), 32, 64);                      \
    (LOW) = hi ? _sb : (A);                                                     \
    (HIW) = hi ? (B) : _sa;                                                     \
  } while (0)
#endif

__global__ __launch_bounds__(256, 4)
void attn_fwd(const bf16* __restrict__ qg, const bf16* __restrict__ kg,
              const bf16* __restrict__ vg, bf16* __restrict__ yb) {
  __shared__ alignas(16) bf16 Ks[3][64 * 64];
  __shared__ alignas(16) bf16 Vs[3][64 * 64];   // V^T tile: [d][k_local]
  const int tid = threadIdx.x;
  const int lane = tid & 63, wid = tid >> 6;
  const int hi = lane >> 5, lq = lane & 31;
  const int xr = (lq & 7) << 4;
  const int bh = blockIdx.y;
  const int NQ = T_ / 128;

  const char* kbase = (const char*)(kg + (size_t)bh * T_ * D_);
  const char* vbase = (const char*)(vg + (size_t)bh * D_ * T_);
  const int b_ = bh >> 4, h = bh & 15;

#define STAGE(BF, TT) do {                                                     \
    _Pragma("unroll")                                                          \
    for (int j_ = 0; j_ < 2; ++j_) {                                           \
      int s_ = j_ * 256 + tid;                                                 \
      int row_ = s_ >> 3;                                                      \
      int scb_ = ((s_ & 7) << 4) ^ ((row_ & 7) << 4);                          \
      gld16(kbase + (size_t)((TT) * 64 + row_) * 128 + scb_,                   \
            (char*)Ks[BF] + s_ * 16);                                          \
      gld16(vbase + (size_t)row_ * (T_ * 2) + (TT) * 128 + scb_,               \
            (char*)Vs[BF] + s_ * 16);                                          \
    }                                                                          \
  } while (0)

  for (int ph = 0; ph < 2; ++ph) {
    const int qblk = ph ? (int)blockIdx.x : (NQ - 1 - (int)blockIdx.x);
    const int wq0 = qblk * 128 + wid * 32;
    const int qrow = wq0 + lq;
    const int nt = 2 * qblk + 2;

    if (ph) __builtin_amdgcn_s_barrier();   // all waves done reading LDS of ph0
    STAGE(0, 0);
    STAGE(1, 1);

    // Q B-fragments: lane holds q-col = qrow, d = 16s + 8hi + e
    const bf16* qptr = qg + ((size_t)bh * T_ + qrow) * D_ + hi * 8;
    bf16x8 qf[4];
#pragma unroll
    for (int s = 0; s < 4; s++) {
      qf[s] = *(const bf16x8*)(qptr + 16 * s);
      asm volatile("" : "+v"(qf[s]));
    }

    f32x16 o[2] = {};              // O^T: block db rows d=32db+crow, col q=lq
    float mrow = NEG_INF, lrow = 0.f;

    for (int t = 0; t < nt; ++t) {
      if (t + 1 < nt) asm volatile("s_waitcnt vmcnt(4)" ::: "memory");
      else            asm volatile("s_waitcnt vmcnt(0)" ::: "memory");
      __builtin_amdgcn_s_barrier();
      asm volatile("" ::: "memory");
      if (t + 2 < nt) STAGE((t + 2) % 3, t + 2);

      const char* Kc = (const char*)Ks[t % 3];
      const char* Vc = (const char*)Vs[t % 3];

      // S^T[k][q] for this wave's 32 q cols; 2 blocks of 32 k
      f32x16 S[2] = {};
      __builtin_amdgcn_s_setprio(1);
#pragma unroll
      for (int s = 0; s < 4; s++) {
#pragma unroll
        for (int b = 0; b < 2; b++) {
          bf16x8 kf = *(const bf16x8*)(Kc + (b * 32 + lq) * 128 +
                                       ((32 * s + 16 * hi) ^ xr));
          S[b] = __builtin_amdgcn_mfma_f32_32x32x16_bf16(kf, qf[s], S[b], 0, 0, 0);
        }
      }
      __builtin_amdgcn_s_setprio(0);

      // causal mask (raw-score domain)
      if (t >= nt - 2) {
#pragma unroll
        for (int b = 0; b < 2; b++)
#pragma unroll
          for (int r = 0; r < 16; r++) {
            int kgl = t * 64 + b * 32 + (r & 3) + 8 * (r >> 2) + 4 * hi;
            if (kgl > qrow) S[b][r] = NEG_INF;
          }
      }

      // online softmax, fully in-register (one cross-lane op per reduce)
      float tm = NEG_INF;
#pragma unroll
      for (int b = 0; b < 2; b++)
#pragma unroll
        for (int r = 0; r < 16; r++) tm = fmaxf(tm, S[b][r]);
      tm = fmaxf(tm, __shfl_xor(tm, 32, 64));

      float mn = fmaxf(mrow, 0.125f * tm);
      float alpha = __expf(mrow - mn);     // exp(-inf)=0 on first tile
      mrow = mn;
      float rs = 0.f;
#pragma unroll
      for (int b = 0; b < 2; b++)
#pragma unroll
        for (int r = 0; r < 16; r++) {
          float e = __expf(fmaf(S[b][r], 0.125f, -mn));
          S[b][r] = e;
          rs += e;
        }
      rs += __shfl_xor(rs, 32, 64);
      lrow = lrow * alpha + rs;
#pragma unroll
      for (int db = 0; db < 2; db++)
#pragma unroll
        for (int r = 0; r < 16; r++) o[db][r] *= alpha;

      // O^T += V^T * P^T ; P^T B-fragment built via cvt_pk + permlane32_swap
      __builtin_amdgcn_s_setprio(1);
#pragma unroll
      for (int ks = 0; ks < 4; ks++) {
        const int b = ks >> 1, hf = ks & 1;
        unsigned A0 = cvtpk(S[b][8 * hf + 0], S[b][8 * hf + 1]);
        unsigned A1 = cvtpk(S[b][8 * hf + 2], S[b][8 * hf + 3]);
        unsigned B0 = cvtpk(S[b][8 * hf + 4], S[b][8 * hf + 5]);
        unsigned B1 = cvtpk(S[b][8 * hf + 6], S[b][8 * hf + 7]);
        unsigned w0, w1, w2, w3;
        PERMSWAP(A0, B0, w0, w2);
        PERMSWAP(A1, B1, w1, w3);
        u32x4 wv = {w0, w1, w2, w3};
        bf16x8 pf = __builtin_bit_cast(bf16x8, wv);
#pragma unroll
        for (int db = 0; db < 2; db++) {
          bf16x8 vf = *(const bf16x8*)(Vc + (db * 32 + lq) * 128 +
                                       ((32 * ks + 16 * hi) ^ xr));
          o[db] = __builtin_amdgcn_mfma_f32_32x32x16_bf16(vf, pf, o[db], 0, 0, 0);
        }
      }
      __builtin_amdgcn_s_setprio(0);
    }

    // epilogue: O^T lane holds q=qrow col; d = 32db + 8rq + 4hi + rr
    float inv = 1.f / lrow;
    bf16* yrow = yb + ((size_t)(b_ * T_ + qrow)) * C_ + h * 64 + hi * 4;
#pragma unroll
    for (int db = 0; db < 2; db++)
#pragma unroll
      for (int rq = 0; rq < 4; rq++) {
        unsigned w0 = cvtpk(o[db][4 * rq + 0] * inv, o[db][4 * rq + 1] * inv);
        unsigned w1 = cvtpk(o[db][4 * rq + 2] * inv, o[db][4 * rq + 3] * inv);
        u32x2 wv = {w0, w1};
        *(u32x2*)(yrow + db * 32 + rq * 8) = wv;
      }
  }
#undef STAGE
}

// ---------------- launch ----------------

extern "C" void kernel_launch(void* const* d_in, const int* in_sizes, int n_in,
                              void* d_out, int out_size, void* d_ws, size_t ws_size,
                              hipStream_t stream) {
  (void)in_sizes; (void)n_in; (void)out_size; (void)ws_size;
  const float* x      = (const float*)d_in[0];
  const float* w_attn = (const float*)d_in[1];
  const float* b_attn = (const float*)d_in[2];
  const float* w_proj = (const float*)d_in[3];
  const float* b_proj = (const float*)d_in[4];
  float* out = (float*)d_out;

  char* ws = (char*)d_ws;
  bf16* x_bf = (bf16*)ws;  ws += (size_t)BT_ * C_ * 2;      // 16 MB
  bf16* wat  = (bf16*)ws;  ws += (size_t)3 * C_ * C_ * 2;   //  6 MB  [3C][C]
  bf16* wpt  = (bf16*)ws;  ws += (size_t)C_ * C_ * 2;       //  2 MB  [C][C]
  bf16* qbuf = (bf16*)ws;  ws += (size_t)BT_ * C_ * 2;      // 16 MB  [B,H,T,D]
  bf16* kbuf = (bf16*)ws;  ws += (size_t)BT_ * C_ * 2;      // 16 MB  [B,H,T,D]
  bf16* vbuf = (bf16*)ws;  ws += (size_t)BT_ * C_ * 2;      // 16 MB  [B,H,D,T]
  bf16* ybuf = (bf16*)ws;                                    // 16 MB  [B,T,C]

  cast_x<<<(BT_ * C_ / 4) / 256, 256, 0, stream>>>(x, x_bf);
  transpose_cast<<<dim3(3 * C_ / 32, C_ / 32), dim3(32, 8), 0, stream>>>(w_attn, wat, C_, 3 * C_);
  transpose_cast<<<dim3(C_ / 32, C_ / 32), dim3(32, 8), 0, stream>>>(w_proj, wpt, C_, C_);

  gemm_bt<0><<<dim3(3 * C_ / 256, BT_ / 128), 512, 0, stream>>>(
      x_bf, wat, b_attn, nullptr, qbuf, kbuf, vbuf, BT_, 3 * C_, C_);

  attn_fwd<<<dim3(T_ / 256, B_ * H_), 256, 0, stream>>>(qbuf, kbuf, vbuf, ybuf);

  gemm_bt<1><<<dim3(C_ / 256, BT_ / 128), 512, 0, stream>>>(
      ybuf, wpt, b_proj, out, nullptr, nullptr, nullptr, BT_, C_, C_);
}

// Round 8
// 288.947 us; speedup vs baseline: 1.0657x; 1.0001x over previous
//
#include <hip/hip_runtime.h>
#include <hip/hip_bf16.h>

typedef __bf16 bf16;
typedef __attribute__((ext_vector_type(4))) __bf16 bf16x4;
typedef __attribute__((ext_vector_type(8))) __bf16 bf16x8;
typedef __attribute__((ext_vector_type(4))) float f32x4;
typedef __attribute__((ext_vector_type(16))) float f32x16;
typedef __attribute__((ext_vector_type(2))) unsigned u32x2;
typedef __attribute__((ext_vector_type(4))) unsigned u32x4;

#define B_ 4
#define T_ 2048
#define C_ 1024
#define H_ 16
#define D_ 64
#define BT_ (B_*T_)

#define NEG_INF (-__builtin_inff())

__device__ __forceinline__ void gld16(const void* g, void* l) {
  __builtin_amdgcn_global_load_lds(
      (const __attribute__((address_space(1))) void*)g,
      (__attribute__((address_space(3))) void*)l, 16, 0, 0);
}

__device__ __forceinline__ unsigned cvtpk(float lo, float hi) {
  unsigned r;
  asm("v_cvt_pk_bf16_f32 %0, %1, %2" : "=v"(r) : "v"(lo), "v"(hi));
  return r;
}

// ---------------- preprocessing ----------------

__global__ void cast_x(const float* __restrict__ in, bf16* __restrict__ out) {
  int i = blockIdx.x * 256 + threadIdx.x;
  f32x4 v = reinterpret_cast<const f32x4*>(in)[i];
  bf16x4 o;
  o[0] = (bf16)v[0]; o[1] = (bf16)v[1]; o[2] = (bf16)v[2]; o[3] = (bf16)v[3];
  reinterpret_cast<bf16x4*>(out)[i] = o;
}

// in [R][Cc] fp32  ->  out [Cc][R] bf16
__global__ void transpose_cast(const float* __restrict__ in, bf16* __restrict__ out,
                               int R, int Cc) {
  __shared__ float tile[32][33];
  int tx = threadIdx.x, ty = threadIdx.y;
  int x  = blockIdx.x * 32 + tx;
  int y0 = blockIdx.y * 32;
#pragma unroll
  for (int j = 0; j < 32; j += 8)
    tile[ty + j][tx] = in[(size_t)(y0 + ty + j) * Cc + x];
  __syncthreads();
  int ox  = y0 + tx;
  int oy0 = blockIdx.x * 32;
#pragma unroll
  for (int j = 0; j < 32; j += 8)
    out[(size_t)(oy0 + ty + j) * R + ox] = (bf16)tile[tx][ty + j];
}

// ---------------- GEMM: C[M][N] = A[M][K] @ Bt[N][K]^T + bias ----------------
// 256x128 tile, BK=64, 8 waves (2M x 4N), wave owns 128x32.
// 3-buffer depth-2 prefetch, counted vmcnt(6), ONE barrier per K-tile.
// 128B LDS rows: 16B-slot XOR row&7 swizzle on BOTH sides (zero excess conflict).
// XCD m-minor mapping: B n-panel L2-resident across 4 m-neighbors.

template<int EPI>
__global__ __launch_bounds__(512, 2)
void gemm_bt(const bf16* __restrict__ A, const bf16* __restrict__ Bt,
             const float* __restrict__ bias, float* __restrict__ outF,
             bf16* __restrict__ qb, bf16* __restrict__ kb, bf16* __restrict__ vb,
             int M, int N, int K) {
  __shared__ alignas(16) bf16 As[3][256 * 64];   // 96 KB
  __shared__ alignas(16) bf16 Bs[3][128 * 64];   // 48 KB
  const int tid = threadIdx.x;
  const int lane = tid & 63, wid = tid >> 6;
  const int wm = wid >> 2, wn = wid & 3;         // 2x4 waves; wave = 128m x 32n
  const int lr = lane & 15, lg = lane >> 4;

  // XCD-aware, m-minor within XCD
  const int nbx = gridDim.x;                     // n-tiles (128 wide)
  const int bid = blockIdx.y * nbx + blockIdx.x;
  const int xcd = bid & 7, j = bid >> 3;
  const int mpx = gridDim.y >> 3;                // m-tiles per XCD (=4)
  const int m0 = (xcd * mpx + j % mpx) * 256;
  const int n0 = (j / mpx) * 128;

  f32x4 acc[8][2] = {};

  // stage K-tile KT into buffer BF. A: 4 slots/thread, B: 2 slots/thread.
  // LDS dest linear (slot S*16B); global src slot = (S&7) ^ (row&7).
#define GSTAGE(BF, KT) do {                                                    \
    const size_t kk_ = (size_t)(KT) * 64;                                      \
    _Pragma("unroll")                                                          \
    for (int j_ = 0; j_ < 4; ++j_) {                                           \
      int S_ = j_ * 512 + tid;                                                 \
      int row_ = S_ >> 3, sl_ = (S_ & 7) ^ (row_ & 7);                         \
      gld16(A + (size_t)(m0 + row_) * K + kk_ + (sl_ << 3), As[BF] + S_ * 8);  \
    }                                                                          \
    _Pragma("unroll")                                                          \
    for (int j_ = 0; j_ < 2; ++j_) {                                           \
      int S_ = j_ * 512 + tid;                                                 \
      int row_ = S_ >> 3, sl_ = (S_ & 7) ^ (row_ & 7);                         \
      gld16(Bt + (size_t)(n0 + row_) * K + kk_ + (sl_ << 3), Bs[BF] + S_ * 8); \
    }                                                                          \
  } while (0)

  const int ktiles = K >> 6;                     // 16
  GSTAGE(0, 0);
  GSTAGE(1, 1);
  for (int kt = 0; kt < ktiles; ++kt) {
    if (kt + 1 < ktiles) asm volatile("s_waitcnt vmcnt(6)" ::: "memory");
    else                 asm volatile("s_waitcnt vmcnt(0)" ::: "memory");
    __builtin_amdgcn_s_barrier();
    asm volatile("" ::: "memory");
    if (kt + 2 < ktiles) GSTAGE((kt + 2) % 3, kt + 2);

    const bf16* Ac = As[kt % 3];
    const bf16* Bc = Bs[kt % 3];

    // B fragments: rows wn*32 + j*16 + lr, k-slice s (32 elems)
    bf16x8 bfr[2][2];
#pragma unroll
    for (int j2 = 0; j2 < 2; j2++) {
      int row = wn * 32 + j2 * 16 + lr;
#pragma unroll
      for (int s = 0; s < 2; s++) {
        int slot = (s * 4 + lg) ^ (row & 7);
        bfr[j2][s] = *(const bf16x8*)(Bc + (row << 6) + (slot << 3));
      }
    }
#pragma unroll
    for (int mh = 0; mh < 2; mh++) {
      bf16x8 af[4][2];
#pragma unroll
      for (int i = 0; i < 4; i++) {
        int row = wm * 128 + mh * 64 + i * 16 + lr;
#pragma unroll
        for (int s = 0; s < 2; s++) {
          int slot = (s * 4 + lg) ^ (row & 7);
          af[i][s] = *(const bf16x8*)(Ac + (row << 6) + (slot << 3));
        }
      }
      __builtin_amdgcn_s_setprio(1);
#pragma unroll
      for (int i = 0; i < 4; i++)
#pragma unroll
        for (int j2 = 0; j2 < 2; j2++) {
          f32x4 a = acc[mh * 4 + i][j2];
          a = __builtin_amdgcn_mfma_f32_16x16x32_bf16(af[i][0], bfr[j2][0], a, 0, 0, 0);
          a = __builtin_amdgcn_mfma_f32_16x16x32_bf16(af[i][1], bfr[j2][1], a, 0, 0, 0);
          acc[mh * 4 + i][j2] = a;
        }
      __builtin_amdgcn_s_setprio(0);
    }
  }
#undef GSTAGE

  if (EPI == 1) {
#pragma unroll
    for (int a = 0; a < 8; a++) {
      int row = m0 + wm * 128 + a * 16 + lg * 4;
#pragma unroll
      for (int j2 = 0; j2 < 2; j2++) {
        int col = n0 + wn * 32 + j2 * 16 + lr;
        float bv = bias[col];
#pragma unroll
        for (int r = 0; r < 4; r++)
          outF[(size_t)(row + r) * N + col] = acc[a][j2][r] + bv;
      }
    }
  } else {
    const int sect = n0 >> 10;                   // 0=q 1=k 2=v (uniform per block)
#pragma unroll
    for (int a = 0; a < 8; a++) {
      int row = m0 + wm * 128 + a * 16 + lg * 4;
#pragma unroll
      for (int j2 = 0; j2 < 2; j2++) {
        int col = n0 + wn * 32 + j2 * 16 + lr;
        float bv = bias[col];
        int cm = col & 1023;
        int h = cm >> 6, d = cm & 63;
#pragma unroll
        for (int r = 0; r < 4; r++) {
          float v = acc[a][j2][r] + bv;
          int rt = row + r;
          int b = rt >> 11, t = rt & 2047;
          bf16 o = (bf16)v;
          size_t bh = (size_t)(b * H_ + h);
          if (sect == 0)      qb[(bh * T_ + t) * D_ + d] = o;   // [B,H,T,D]
          else if (sect == 1) kb[(bh * T_ + t) * D_ + d] = o;   // [B,H,T,D]
          else                vb[(bh * D_ + d) * T_ + t] = o;   // [B,H,D,T] (V^T)
        }
      }
    }
  }
}

// ---------------- flash attention (32x32 swapped-operand, in-register softmax) ----
// grid: (T/256, B*H); 256 threads = 4 waves, wave w owns 32 q rows.
// Work-balanced: block p handles qblk {NQ-1-p} then {p} -> 34 tiles/block flat.
// 3-buffer depth-2 prefetch, counted vmcnt(4) (T3/T4): load->wait gap = 2 tiles.

#if __has_builtin(__builtin_amdgcn_permlane32_swap)
#define PERMSWAP(A, B, LOW, HIW) do {                                           \
    auto _r = __builtin_amdgcn_permlane32_swap((unsigned)(A), (unsigned)(B),    \
                                               false, false);                   \
    __builtin_memcpy(&(LOW), &_r, 4);                                           \
    __builtin_memcpy(&(HIW), (const char*)&_r + 4, 4);                          \
  } while (0)
#else
#define PERMSWAP(A, B, LOW, HIW) do {                                           \
    unsigned _sb = (unsigned)__shfl_xor((int)(B), 32, 64);                      \
    unsigned _sa = (unsigned)__shfl_xor((int)(A), 32, 64);                      \
    (LOW) = hi ? _sb : (A);                                                     \
    (HIW) = hi ? (B) : _sa;                                                     \
  } while (0)
#endif

__global__ __launch_bounds__(256, 4)
void attn_fwd(const bf16* __restrict__ qg, const bf16* __restrict__ kg,
              const bf16* __restrict__ vg, bf16* __restrict__ yb) {
  __shared__ alignas(16) bf16 Ks[3][64 * 64];
  __shared__ alignas(16) bf16 Vs[3][64 * 64];   // V^T tile: [d][k_local]
  const int tid = threadIdx.x;
  const int lane = tid & 63, wid = tid >> 6;
  const int hi = lane >> 5, lq = lane & 31;
  const int xr = (lq & 7) << 4;
  const int bh = blockIdx.y;
  const int NQ = T_ / 128;

  const char* kbase = (const char*)(kg + (size_t)bh * T_ * D_);
  const char* vbase = (const char*)(vg + (size_t)bh * D_ * T_);
  const int b_ = bh >> 4, h = bh & 15;

#define STAGE(BF, TT) do {                                                     \
    _Pragma("unroll")                                                          \
    for (int j_ = 0; j_ < 2; ++j_) {                                           \
      int s_ = j_ * 256 + tid;                                                 \
      int row_ = s_ >> 3;                                                      \
      int scb_ = ((s_ & 7) << 4) ^ ((row_ & 7) << 4);                          \
      gld16(kbase + (size_t)((TT) * 64 + row_) * 128 + scb_,                   \
            (char*)Ks[BF] + s_ * 16);                                          \
      gld16(vbase + (size_t)row_ * (T_ * 2) + (TT) * 128 + scb_,               \
            (char*)Vs[BF] + s_ * 16);                                          \
    }                                                                          \
  } while (0)

  for (int ph = 0; ph < 2; ++ph) {
    const int qblk = ph ? (int)blockIdx.x : (NQ - 1 - (int)blockIdx.x);
    const int wq0 = qblk * 128 + wid * 32;
    const int qrow = wq0 + lq;
    const int nt = 2 * qblk + 2;

    if (ph) __builtin_amdgcn_s_barrier();   // all waves done reading LDS of ph0
    STAGE(0, 0);
    STAGE(1, 1);

    // Q B-fragments: lane holds q-col = qrow, d = 16s + 8hi + e
    const bf16* qptr = qg + ((size_t)bh * T_ + qrow) * D_ + hi * 8;
    bf16x8 qf[4];
#pragma unroll
    for (int s = 0; s < 4; s++) {
      qf[s] = *(const bf16x8*)(qptr + 16 * s);
      asm volatile("" : "+v"(qf[s]));
    }

    f32x16 o[2] = {};              // O^T: block db rows d=32db+crow, col q=lq
    float mrow = NEG_INF, lrow = 0.f;

    for (int t = 0; t < nt; ++t) {
      if (t + 1 < nt) asm volatile("s_waitcnt vmcnt(4)" ::: "memory");
      else            asm volatile("s_waitcnt vmcnt(0)" ::: "memory");
      __builtin_amdgcn_s_barrier();
      asm volatile("" ::: "memory");
      if (t + 2 < nt) STAGE((t + 2) % 3, t + 2);

      const char* Kc = (const char*)Ks[t % 3];
      const char* Vc = (const char*)Vs[t % 3];

      // S^T[k][q] for this wave's 32 q cols; 2 blocks of 32 k
      f32x16 S[2] = {};
      __builtin_amdgcn_s_setprio(1);
#pragma unroll
      for (int s = 0; s < 4; s++) {
#pragma unroll
        for (int b = 0; b < 2; b++) {
          bf16x8 kf = *(const bf16x8*)(Kc + (b * 32 + lq) * 128 +
                                       ((32 * s + 16 * hi) ^ xr));
          S[b] = __builtin_amdgcn_mfma_f32_32x32x16_bf16(kf, qf[s], S[b], 0, 0, 0);
        }
      }
      __builtin_amdgcn_s_setprio(0);

      // causal mask (raw-score domain)
      if (t >= nt - 2) {
#pragma unroll
        for (int b = 0; b < 2; b++)
#pragma unroll
          for (int r = 0; r < 16; r++) {
            int kgl = t * 64 + b * 32 + (r & 3) + 8 * (r >> 2) + 4 * hi;
            if (kgl > qrow) S[b][r] = NEG_INF;
          }
      }

      // online softmax, fully in-register (one cross-lane op per reduce)
      float tm = NEG_INF;
#pragma unroll
      for (int b = 0; b < 2; b++)
#pragma unroll
        for (int r = 0; r < 16; r++) tm = fmaxf(tm, S[b][r]);
      tm = fmaxf(tm, __shfl_xor(tm, 32, 64));

      float mn = fmaxf(mrow, 0.125f * tm);
      float alpha = __expf(mrow - mn);     // exp(-inf)=0 on first tile
      mrow = mn;
      float rs = 0.f;
#pragma unroll
      for (int b = 0; b < 2; b++)
#pragma unroll
        for (int r = 0; r < 16; r++) {
          float e = __expf(fmaf(S[b][r], 0.125f, -mn));
          S[b][r] = e;
          rs += e;
        }
      rs += __shfl_xor(rs, 32, 64);
      lrow = lrow * alpha + rs;
#pragma unroll
      for (int db = 0; db < 2; db++)
#pragma unroll
        for (int r = 0; r < 16; r++) o[db][r] *= alpha;

      // O^T += V^T * P^T ; P^T B-fragment built via cvt_pk + permlane32_swap
      __builtin_amdgcn_s_setprio(1);
#pragma unroll
      for (int ks = 0; ks < 4; ks++) {
        const int b = ks >> 1, hf = ks & 1;
        unsigned A0 = cvtpk(S[b][8 * hf + 0], S[b][8 * hf + 1]);
        unsigned A1 = cvtpk(S[b][8 * hf + 2], S[b][8 * hf + 3]);
        unsigned B0 = cvtpk(S[b][8 * hf + 4], S[b][8 * hf + 5]);
        unsigned B1 = cvtpk(S[b][8 * hf + 6], S[b][8 * hf + 7]);
        unsigned w0, w1, w2, w3;
        PERMSWAP(A0, B0, w0, w2);
        PERMSWAP(A1, B1, w1, w3);
        u32x4 wv = {w0, w1, w2, w3};
        bf16x8 pf = __builtin_bit_cast(bf16x8, wv);
#pragma unroll
        for (int db = 0; db < 2; db++) {
          bf16x8 vf = *(const bf16x8*)(Vc + (db * 32 + lq) * 128 +
                                       ((32 * ks + 16 * hi) ^ xr));
          o[db] = __builtin_amdgcn_mfma_f32_32x32x16_bf16(vf, pf, o[db], 0, 0, 0);
        }
      }
      __builtin_amdgcn_s_setprio(0);
    }

    // epilogue: O^T lane holds q=qrow col; d = 32db + 8rq + 4hi + rr
    float inv = 1.f / lrow;
    bf16* yrow = yb + ((size_t)(b_ * T_ + qrow)) * C_ + h * 64 + hi * 4;
#pragma unroll
    for (int db = 0; db < 2; db++)
#pragma unroll
      for (int rq = 0; rq < 4; rq++) {
        unsigned w0 = cvtpk(o[db][4 * rq + 0] * inv, o[db][4 * rq + 1] * inv);
        unsigned w1 = cvtpk(o[db][4 * rq + 2] * inv, o[db][4 * rq + 3] * inv);
        u32x2 wv = {w0, w1};
        *(u32x2*)(yrow + db * 32 + rq * 8) = wv;
      }
  }
#undef STAGE
}

// ---------------- launch ----------------

extern "C" void kernel_launch(void* const* d_in, const int* in_sizes, int n_in,
                              void* d_out, int out_size, void* d_ws, size_t ws_size,
                              hipStream_t stream) {
  (void)in_sizes; (void)n_in; (void)out_size; (void)ws_size;
  const float* x      = (const float*)d_in[0];
  const float* w_attn = (const float*)d_in[1];
  const float* b_attn = (const float*)d_in[2];
  const float* w_proj = (const float*)d_in[3];
  const float* b_proj = (const float*)d_in[4];
  float* out = (float*)d_out;

  char* ws = (char*)d_ws;
  bf16* x_bf = (bf16*)ws;  ws += (size_t)BT_ * C_ * 2;      // 16 MB
  bf16* wat  = (bf16*)ws;  ws += (size_t)3 * C_ * C_ * 2;   //  6 MB  [3C][C]
  bf16* wpt  = (bf16*)ws;  ws += (size_t)C_ * C_ * 2;       //  2 MB  [C][C]
  bf16* qbuf = (bf16*)ws;  ws += (size_t)BT_ * C_ * 2;      // 16 MB  [B,H,T,D]
  bf16* kbuf = (bf16*)ws;  ws += (size_t)BT_ * C_ * 2;      // 16 MB  [B,H,T,D]
  bf16* vbuf = (bf16*)ws;  ws += (size_t)BT_ * C_ * 2;      // 16 MB  [B,H,D,T]
  bf16* ybuf = (bf16*)ws;                                    // 16 MB  [B,T,C]

  cast_x<<<(BT_ * C_ / 4) / 256, 256, 0, stream>>>(x, x_bf);
  transpose_cast<<<dim3(3 * C_ / 32, C_ / 32), dim3(32, 8), 0, stream>>>(w_attn, wat, C_, 3 * C_);
  transpose_cast<<<dim3(C_ / 32, C_ / 32), dim3(32, 8), 0, stream>>>(w_proj, wpt, C_, C_);

  gemm_bt<0><<<dim3(3 * C_ / 128, BT_ / 256), 512, 0, stream>>>(
      x_bf, wat, b_attn, nullptr, qbuf, kbuf, vbuf, BT_, 3 * C_, C_);

  attn_fwd<<<dim3(T_ / 256, B_ * H_), 256, 0, stream>>>(qbuf, kbuf, vbuf, ybuf);

  gemm_bt<1><<<dim3(C_ / 128, BT_ / 256), 512, 0, stream>>>(
      ybuf, wpt, b_proj, out, nullptr, nullptr, nullptr, BT_, C_, C_);
}

// Round 9
// 273.092 us; speedup vs baseline: 1.1276x; 1.0581x over previous
//
#include <hip/hip_runtime.h>
#include <hip/hip_bf16.h>

typedef __bf16 bf16;
typedef __attribute__((ext_vector_type(4))) __bf16 bf16x4;
typedef __attribute__((ext_vector_type(8))) __bf16 bf16x8;
typedef __attribute__((ext_vector_type(4))) float f32x4;
typedef __attribute__((ext_vector_type(16))) float f32x16;
typedef __attribute__((ext_vector_type(2))) unsigned u32x2;
typedef __attribute__((ext_vector_type(4))) unsigned u32x4;

#define B_ 4
#define T_ 2048
#define C_ 1024
#define H_ 16
#define D_ 64
#define BT_ (B_*T_)

#define NEG_INF (-__builtin_inff())

__device__ __forceinline__ void gld16(const void* g, void* l) {
  __builtin_amdgcn_global_load_lds(
      (const __attribute__((address_space(1))) void*)g,
      (__attribute__((address_space(3))) void*)l, 16, 0, 0);
}

__device__ __forceinline__ unsigned cvtpk(float lo, float hi) {
  unsigned r;
  asm("v_cvt_pk_bf16_f32 %0, %1, %2" : "=v"(r) : "v"(lo), "v"(hi));
  return r;
}

// ---------------- preprocessing ----------------

__global__ void cast_x(const float* __restrict__ in, bf16* __restrict__ out) {
  int i = blockIdx.x * 256 + threadIdx.x;
  f32x4 v = reinterpret_cast<const f32x4*>(in)[i];
  bf16x4 o;
  o[0] = (bf16)v[0]; o[1] = (bf16)v[1]; o[2] = (bf16)v[2]; o[3] = (bf16)v[3];
  reinterpret_cast<bf16x4*>(out)[i] = o;
}

// in [R][Cc] fp32  ->  out [Cc][R] bf16
__global__ void transpose_cast(const float* __restrict__ in, bf16* __restrict__ out,
                               int R, int Cc) {
  __shared__ float tile[32][33];
  int tx = threadIdx.x, ty = threadIdx.y;
  int x  = blockIdx.x * 32 + tx;
  int y0 = blockIdx.y * 32;
#pragma unroll
  for (int j = 0; j < 32; j += 8)
    tile[ty + j][tx] = in[(size_t)(y0 + ty + j) * Cc + x];
  __syncthreads();
  int ox  = y0 + tx;
  int oy0 = blockIdx.x * 32;
#pragma unroll
  for (int j = 0; j < 32; j += 8)
    out[(size_t)(oy0 + ty + j) * R + ox] = (bf16)tile[tx][ty + j];
}

// ---------------- GEMM: C[M][N] = A[M][K] @ Bt[N][K]^T + bias ----------------
// 128x128 tile, BK=32, 4 waves (2x2, 64x64 each) -> m97 geometry, 3 blocks/CU.
// 2-buffer double-buffering, counted vmcnt(4), ONE barrier per K-step.
// 64B LDS rows: 16B-slot XOR (row>>1)&3 on BOTH sides (2-way max = free).
// XCD m-minor mapping: B n-panel + A m-panels L2-resident per XCD.

template<int EPI>
__global__ __launch_bounds__(256, 3)
void gemm_bt(const bf16* __restrict__ A, const bf16* __restrict__ Bt,
             const float* __restrict__ bias, float* __restrict__ outF,
             bf16* __restrict__ qb, bf16* __restrict__ kb, bf16* __restrict__ vb,
             int M, int N, int K) {
  __shared__ alignas(16) bf16 As[2][128 * 32];   // 16 KB
  __shared__ alignas(16) bf16 Bs[2][128 * 32];   // 16 KB
  const int tid = threadIdx.x;
  const int lane = tid & 63, wid = tid >> 6;
  const int wm = wid >> 1, wn = wid & 1;         // 2x2 waves, 64x64 each
  const int lr = lane & 15, lg = lane >> 4;

  // XCD-aware, m-minor within XCD (B n-panel reused by 8 consecutive blocks)
  const int nbx = gridDim.x;
  const int bid = blockIdx.y * nbx + blockIdx.x;
  const int xcd = bid & 7, j = bid >> 3;
  const int mpx = gridDim.y >> 3;                // m-tiles per XCD (=8)
  const int m0 = (xcd * mpx + j % mpx) * 128;
  const int n0 = (j / mpx) * 128;

  f32x4 acc[4][4] = {};

  // stage K-step KT into buffer BF: A 2 slots/thread, B 2 slots/thread.
  // LDS dest linear; global src 16B-slot = (S&3) ^ ((row>>1)&3).
#define GSTAGE(BF, KT) do {                                                    \
    const int k0_ = (KT) << 5;                                                 \
    _Pragma("unroll")                                                          \
    for (int j_ = 0; j_ < 2; ++j_) {                                           \
      int S_ = j_ * 256 + tid;                                                 \
      int row_ = S_ >> 2, sl_ = (S_ & 3) ^ ((row_ >> 1) & 3);                  \
      gld16(A + (size_t)(m0 + row_) * K + k0_ + (sl_ << 3), As[BF] + S_ * 8);  \
    }                                                                          \
    _Pragma("unroll")                                                          \
    for (int j_ = 0; j_ < 2; ++j_) {                                           \
      int S_ = j_ * 256 + tid;                                                 \
      int row_ = S_ >> 2, sl_ = (S_ & 3) ^ ((row_ >> 1) & 3);                  \
      gld16(Bt + (size_t)(n0 + row_) * K + k0_ + (sl_ << 3), Bs[BF] + S_ * 8); \
    }                                                                          \
  } while (0)

  const int ktiles = K >> 5;                     // 32
  GSTAGE(0, 0);
  for (int kt = 0; kt < ktiles; ++kt) {
    __builtin_amdgcn_s_barrier();                // all waves done reading buf[(kt+1)&1]
    if (kt + 1 < ktiles) {
      GSTAGE((kt + 1) & 1, kt + 1);
      asm volatile("s_waitcnt vmcnt(4)" ::: "memory");   // stage(kt) complete
    } else {
      asm volatile("s_waitcnt vmcnt(0)" ::: "memory");
    }
    asm volatile("" ::: "memory");

    const bf16* Ac = As[kt & 1];
    const bf16* Bc = Bs[kt & 1];
    bf16x8 af[4], bfr[4];
#pragma unroll
    for (int i = 0; i < 4; i++) {
      int row = wm * 64 + i * 16 + lr;
      int slot = lg ^ ((row >> 1) & 3);
      af[i] = *(const bf16x8*)(Ac + (row << 5) + (slot << 3));
    }
#pragma unroll
    for (int j2 = 0; j2 < 4; j2++) {
      int row = wn * 64 + j2 * 16 + lr;
      int slot = lg ^ ((row >> 1) & 3);
      bfr[j2] = *(const bf16x8*)(Bc + (row << 5) + (slot << 3));
    }
    __builtin_amdgcn_s_setprio(1);
#pragma unroll
    for (int i = 0; i < 4; i++)
#pragma unroll
      for (int j2 = 0; j2 < 4; j2++)
        acc[i][j2] = __builtin_amdgcn_mfma_f32_16x16x32_bf16(af[i], bfr[j2], acc[i][j2], 0, 0, 0);
    __builtin_amdgcn_s_setprio(0);
  }
#undef GSTAGE

  if (EPI == 1) {
#pragma unroll
    for (int i = 0; i < 4; i++) {
      int row = m0 + wm * 64 + i * 16 + lg * 4;
#pragma unroll
      for (int j2 = 0; j2 < 4; j2++) {
        int col = n0 + wn * 64 + j2 * 16 + lr;
        float bv = bias[col];
#pragma unroll
        for (int r = 0; r < 4; r++)
          outF[(size_t)(row + r) * N + col] = acc[i][j2][r] + bv;
      }
    }
  } else {
    const int sect = n0 >> 10;                   // 0=q 1=k 2=v (uniform per block)
#pragma unroll
    for (int i = 0; i < 4; i++) {
      int row = m0 + wm * 64 + i * 16 + lg * 4;
#pragma unroll
      for (int j2 = 0; j2 < 4; j2++) {
        int col = n0 + wn * 64 + j2 * 16 + lr;
        float bv = bias[col];
        int cm = col & 1023;
        int h = cm >> 6, d = cm & 63;
#pragma unroll
        for (int r = 0; r < 4; r++) {
          float v = acc[i][j2][r] + bv;
          int rt = row + r;
          int b = rt >> 11, t = rt & 2047;
          bf16 o = (bf16)v;
          size_t bh = (size_t)(b * H_ + h);
          if (sect == 0)      qb[(bh * T_ + t) * D_ + d] = o;   // [B,H,T,D]
          else if (sect == 1) kb[(bh * T_ + t) * D_ + d] = o;   // [B,H,T,D]
          else                vb[(bh * D_ + d) * T_ + t] = o;   // [B,H,D,T] (V^T)
        }
      }
    }
  }
}

// ---------------- flash attention (32x32 swapped-operand, in-register softmax) ----
// grid: (T/256, B*H); 256 threads = 4 waves, wave w owns 32 q rows.
// Work-balanced: block p handles qblk {NQ-1-p} then {p} -> 34 tiles/block flat.
// 3-buffer depth-2 prefetch, counted vmcnt(4) (T3/T4): load->wait gap = 2 tiles.

#if __has_builtin(__builtin_amdgcn_permlane32_swap)
#define PERMSWAP(A, B, LOW, HIW) do {                                           \
    auto _r = __builtin_amdgcn_permlane32_swap((unsigned)(A), (unsigned)(B),    \
                                               false, false);                   \
    __builtin_memcpy(&(LOW), &_r, 4);                                           \
    __builtin_memcpy(&(HIW), (const char*)&_r + 4, 4);                          \
  } while (0)
#else
#define PERMSWAP(A, B, LOW, HIW) do {                                           \
    unsigned _sb = (unsigned)__shfl_xor((int)(B), 32, 64);                      \
    unsigned _sa = (unsigned)__shfl_xor((int)(A), 32, 64);                      \
    (LOW) = hi ? _sb : (A);                                                     \
    (HIW) = hi ? (B) : _sa;                                                     \
  } while (0)
#endif

__global__ __launch_bounds__(256, 4)
void attn_fwd(const bf16* __restrict__ qg, const bf16* __restrict__ kg,
              const bf16* __restrict__ vg, bf16* __restrict__ yb) {
  __shared__ alignas(16) bf16 Ks[3][64 * 64];
  __shared__ alignas(16) bf16 Vs[3][64 * 64];   // V^T tile: [d][k_local]
  const int tid = threadIdx.x;
  const int lane = tid & 63, wid = tid >> 6;
  const int hi = lane >> 5, lq = lane & 31;
  const int xr = (lq & 7) << 4;
  const int bh = blockIdx.y;
  const int NQ = T_ / 128;

  const char* kbase = (const char*)(kg + (size_t)bh * T_ * D_);
  const char* vbase = (const char*)(vg + (size_t)bh * D_ * T_);
  const int b_ = bh >> 4, h = bh & 15;

#define STAGE(BF, TT) do {                                                     \
    _Pragma("unroll")                                                          \
    for (int j_ = 0; j_ < 2; ++j_) {                                           \
      int s_ = j_ * 256 + tid;                                                 \
      int row_ = s_ >> 3;                                                      \
      int scb_ = ((s_ & 7) << 4) ^ ((row_ & 7) << 4);                          \
      gld16(kbase + (size_t)((TT) * 64 + row_) * 128 + scb_,                   \
            (char*)Ks[BF] + s_ * 16);                                          \
      gld16(vbase + (size_t)row_ * (T_ * 2) + (TT) * 128 + scb_,               \
            (char*)Vs[BF] + s_ * 16);                                          \
    }                                                                          \
  } while (0)

  for (int ph = 0; ph < 2; ++ph) {
    const int qblk = ph ? (int)blockIdx.x : (NQ - 1 - (int)blockIdx.x);
    const int wq0 = qblk * 128 + wid * 32;
    const int qrow = wq0 + lq;
    const int nt = 2 * qblk + 2;

    if (ph) __builtin_amdgcn_s_barrier();   // all waves done reading LDS of ph0
    STAGE(0, 0);
    STAGE(1, 1);

    // Q B-fragments: lane holds q-col = qrow, d = 16s + 8hi + e
    const bf16* qptr = qg + ((size_t)bh * T_ + qrow) * D_ + hi * 8;
    bf16x8 qf[4];
#pragma unroll
    for (int s = 0; s < 4; s++) {
      qf[s] = *(const bf16x8*)(qptr + 16 * s);
      asm volatile("" : "+v"(qf[s]));
    }

    f32x16 o[2] = {};              // O^T: block db rows d=32db+crow, col q=lq
    float mrow = NEG_INF, lrow = 0.f;

    for (int t = 0; t < nt; ++t) {
      if (t + 1 < nt) asm volatile("s_waitcnt vmcnt(4)" ::: "memory");
      else            asm volatile("s_waitcnt vmcnt(0)" ::: "memory");
      __builtin_amdgcn_s_barrier();
      asm volatile("" ::: "memory");
      if (t + 2 < nt) STAGE((t + 2) % 3, t + 2);

      const char* Kc = (const char*)Ks[t % 3];
      const char* Vc = (const char*)Vs[t % 3];

      // S^T[k][q] for this wave's 32 q cols; 2 blocks of 32 k
      f32x16 S[2] = {};
      __builtin_amdgcn_s_setprio(1);
#pragma unroll
      for (int s = 0; s < 4; s++) {
#pragma unroll
        for (int b = 0; b < 2; b++) {
          bf16x8 kf = *(const bf16x8*)(Kc + (b * 32 + lq) * 128 +
                                       ((32 * s + 16 * hi) ^ xr));
          S[b] = __builtin_amdgcn_mfma_f32_32x32x16_bf16(kf, qf[s], S[b], 0, 0, 0);
        }
      }
      __builtin_amdgcn_s_setprio(0);

      // causal mask (raw-score domain)
      if (t >= nt - 2) {
#pragma unroll
        for (int b = 0; b < 2; b++)
#pragma unroll
          for (int r = 0; r < 16; r++) {
            int kgl = t * 64 + b * 32 + (r & 3) + 8 * (r >> 2) + 4 * hi;
            if (kgl > qrow) S[b][r] = NEG_INF;
          }
      }

      // online softmax, fully in-register (one cross-lane op per reduce)
      float tm = NEG_INF;
#pragma unroll
      for (int b = 0; b < 2; b++)
#pragma unroll
        for (int r = 0; r < 16; r++) tm = fmaxf(tm, S[b][r]);
      tm = fmaxf(tm, __shfl_xor(tm, 32, 64));

      float mn = fmaxf(mrow, 0.125f * tm);
      float alpha = __expf(mrow - mn);     // exp(-inf)=0 on first tile
      mrow = mn;
      float rs = 0.f;
#pragma unroll
      for (int b = 0; b < 2; b++)
#pragma unroll
        for (int r = 0; r < 16; r++) {
          float e = __expf(fmaf(S[b][r], 0.125f, -mn));
          S[b][r] = e;
          rs += e;
        }
      rs += __shfl_xor(rs, 32, 64);
      lrow = lrow * alpha + rs;
#pragma unroll
      for (int db = 0; db < 2; db++)
#pragma unroll
        for (int r = 0; r < 16; r++) o[db][r] *= alpha;

      // O^T += V^T * P^T ; P^T B-fragment built via cvt_pk + permlane32_swap
      __builtin_amdgcn_s_setprio(1);
#pragma unroll
      for (int ks = 0; ks < 4; ks++) {
        const int b = ks >> 1, hf = ks & 1;
        unsigned A0 = cvtpk(S[b][8 * hf + 0], S[b][8 * hf + 1]);
        unsigned A1 = cvtpk(S[b][8 * hf + 2], S[b][8 * hf + 3]);
        unsigned B0 = cvtpk(S[b][8 * hf + 4], S[b][8 * hf + 5]);
        unsigned B1 = cvtpk(S[b][8 * hf + 6], S[b][8 * hf + 7]);
        unsigned w0, w1, w2, w3;
        PERMSWAP(A0, B0, w0, w2);
        PERMSWAP(A1, B1, w1, w3);
        u32x4 wv = {w0, w1, w2, w3};
        bf16x8 pf = __builtin_bit_cast(bf16x8, wv);
#pragma unroll
        for (int db = 0; db < 2; db++) {
          bf16x8 vf = *(const bf16x8*)(Vc + (db * 32 + lq) * 128 +
                                       ((32 * ks + 16 * hi) ^ xr));
          o[db] = __builtin_amdgcn_mfma_f32_32x32x16_bf16(vf, pf, o[db], 0, 0, 0);
        }
      }
      __builtin_amdgcn_s_setprio(0);
    }

    // epilogue: O^T lane holds q=qrow col; d = 32db + 8rq + 4hi + rr
    float inv = 1.f / lrow;
    bf16* yrow = yb + ((size_t)(b_ * T_ + qrow)) * C_ + h * 64 + hi * 4;
#pragma unroll
    for (int db = 0; db < 2; db++)
#pragma unroll
      for (int rq = 0; rq < 4; rq++) {
        unsigned w0 = cvtpk(o[db][4 * rq + 0] * inv, o[db][4 * rq + 1] * inv);
        unsigned w1 = cvtpk(o[db][4 * rq + 2] * inv, o[db][4 * rq + 3] * inv);
        u32x2 wv = {w0, w1};
        *(u32x2*)(yrow + db * 32 + rq * 8) = wv;
      }
  }
#undef STAGE
}

// ---------------- launch ----------------

extern "C" void kernel_launch(void* const* d_in, const int* in_sizes, int n_in,
                              void* d_out, int out_size, void* d_ws, size_t ws_size,
                              hipStream_t stream) {
  (void)in_sizes; (void)n_in; (void)out_size; (void)ws_size;
  const float* x      = (const float*)d_in[0];
  const float* w_attn = (const float*)d_in[1];
  const float* b_attn = (const float*)d_in[2];
  const float* w_proj = (const float*)d_in[3];
  const float* b_proj = (const float*)d_in[4];
  float* out = (float*)d_out;

  char* ws = (char*)d_ws;
  bf16* x_bf = (bf16*)ws;  ws += (size_t)BT_ * C_ * 2;      // 16 MB
  bf16* wat  = (bf16*)ws;  ws += (size_t)3 * C_ * C_ * 2;   //  6 MB  [3C][C]
  bf16* wpt  = (bf16*)ws;  ws += (size_t)C_ * C_ * 2;       //  2 MB  [C][C]
  bf16* qbuf = (bf16*)ws;  ws += (size_t)BT_ * C_ * 2;      // 16 MB  [B,H,T,D]
  bf16* kbuf = (bf16*)ws;  ws += (size_t)BT_ * C_ * 2;      // 16 MB  [B,H,T,D]
  bf16* vbuf = (bf16*)ws;  ws += (size_t)BT_ * C_ * 2;      // 16 MB  [B,H,D,T]
  bf16* ybuf = (bf16*)ws;                                    // 16 MB  [B,T,C]

  cast_x<<<(BT_ * C_ / 4) / 256, 256, 0, stream>>>(x, x_bf);
  transpose_cast<<<dim3(3 * C_ / 32, C_ / 32), dim3(32, 8), 0, stream>>>(w_attn, wat, C_, 3 * C_);
  transpose_cast<<<dim3(C_ / 32, C_ / 32), dim3(32, 8), 0, stream>>>(w_proj, wpt, C_, C_);

  gemm_bt<0><<<dim3(3 * C_ / 128, BT_ / 128), 256, 0, stream>>>(
      x_bf, wat, b_attn, nullptr, qbuf, kbuf, vbuf, BT_, 3 * C_, C_);

  attn_fwd<<<dim3(T_ / 256, B_ * H_), 256, 0, stream>>>(qbuf, kbuf, vbuf, ybuf);

  gemm_bt<1><<<dim3(C_ / 128, BT_ / 128), 256, 0, stream>>>(
      ybuf, wpt, b_proj, out, nullptr, nullptr, nullptr, BT_, C_, C_);
}

// Round 10
// 267.793 us; speedup vs baseline: 1.1499x; 1.0198x over previous
//
#include <hip/hip_runtime.h>
#include <hip/hip_bf16.h>

typedef __bf16 bf16;
typedef __attribute__((ext_vector_type(4))) __bf16 bf16x4;
typedef __attribute__((ext_vector_type(8))) __bf16 bf16x8;
typedef __attribute__((ext_vector_type(4))) float f32x4;
typedef __attribute__((ext_vector_type(16))) float f32x16;
typedef __attribute__((ext_vector_type(2))) unsigned u32x2;
typedef __attribute__((ext_vector_type(4))) unsigned u32x4;

#define B_ 4
#define T_ 2048
#define C_ 1024
#define H_ 16
#define D_ 64
#define BT_ (B_*T_)

#define NEG_INF (-__builtin_inff())

__device__ __forceinline__ void gld16(const void* g, void* l) {
  __builtin_amdgcn_global_load_lds(
      (const __attribute__((address_space(1))) void*)g,
      (__attribute__((address_space(3))) void*)l, 16, 0, 0);
}

__device__ __forceinline__ unsigned cvtpk(float lo, float hi) {
  unsigned r;
  asm("v_cvt_pk_bf16_f32 %0, %1, %2" : "=v"(r) : "v"(lo), "v"(hi));
  return r;
}

// ---------------- preprocessing ----------------

__global__ void cast_x(const float* __restrict__ in, bf16* __restrict__ out) {
  int i = blockIdx.x * 256 + threadIdx.x;
  f32x4 v = reinterpret_cast<const f32x4*>(in)[i];
  bf16x4 o;
  o[0] = (bf16)v[0]; o[1] = (bf16)v[1]; o[2] = (bf16)v[2]; o[3] = (bf16)v[3];
  reinterpret_cast<bf16x4*>(out)[i] = o;
}

// in [R][Cc] fp32  ->  out [Cc][R] bf16
__global__ void transpose_cast(const float* __restrict__ in, bf16* __restrict__ out,
                               int R, int Cc) {
  __shared__ float tile[32][33];
  int tx = threadIdx.x, ty = threadIdx.y;
  int x  = blockIdx.x * 32 + tx;
  int y0 = blockIdx.y * 32;
#pragma unroll
  for (int j = 0; j < 32; j += 8)
    tile[ty + j][tx] = in[(size_t)(y0 + ty + j) * Cc + x];
  __syncthreads();
  int ox  = y0 + tx;
  int oy0 = blockIdx.x * 32;
#pragma unroll
  for (int j = 0; j < 32; j += 8)
    out[(size_t)(oy0 + ty + j) * R + ox] = (bf16)tile[tx][ty + j];
}

// ---------------- GEMM: C[M][N] = A[M][K] @ Bt[N][K]^T + bias ----------------
// 128x128 tile, BK=32, 4 waves (2x2, 64x64 each), 3 blocks/CU.
// 3-buffer depth-2 prefetch, counted vmcnt(4), ONE barrier per K-step.
// 64B LDS rows: 16B-slot XOR (row>>1)&3 on BOTH sides (2-way max = free).
// XCD m-minor mapping: A m-panel (4MB) L2-resident per XCD.

template<int EPI>
__global__ __launch_bounds__(256, 3)
void gemm_bt(const bf16* __restrict__ A, const bf16* __restrict__ Bt,
             const float* __restrict__ bias, float* __restrict__ outF,
             bf16* __restrict__ qb, bf16* __restrict__ kb, bf16* __restrict__ vb,
             int M, int N, int K) {
  __shared__ alignas(16) bf16 As[3][128 * 32];   // 24 KB
  __shared__ alignas(16) bf16 Bs[3][128 * 32];   // 24 KB
  const int tid = threadIdx.x;
  const int lane = tid & 63, wid = tid >> 6;
  const int wm = wid >> 1, wn = wid & 1;         // 2x2 waves, 64x64 each
  const int lr = lane & 15, lg = lane >> 4;

  // XCD-aware, m-minor within XCD
  const int nbx = gridDim.x;
  const int bid = blockIdx.y * nbx + blockIdx.x;
  const int xcd = bid & 7, j = bid >> 3;
  const int mpx = gridDim.y >> 3;                // m-tiles per XCD (=8)
  const int m0 = (xcd * mpx + j % mpx) * 128;
  const int n0 = (j / mpx) * 128;

  f32x4 acc[4][4] = {};

  // stage K-step KT into buffer BF: A 2 slots/thread, B 2 slots/thread (4 gld16).
  // LDS dest linear; global src 16B-slot = (S&3) ^ ((row>>1)&3).
#define GSTAGE(BF, KT) do {                                                    \
    const int k0_ = (KT) << 5;                                                 \
    _Pragma("unroll")                                                          \
    for (int j_ = 0; j_ < 2; ++j_) {                                           \
      int S_ = j_ * 256 + tid;                                                 \
      int row_ = S_ >> 2, sl_ = (S_ & 3) ^ ((row_ >> 1) & 3);                  \
      gld16(A + (size_t)(m0 + row_) * K + k0_ + (sl_ << 3), As[BF] + S_ * 8);  \
    }                                                                          \
    _Pragma("unroll")                                                          \
    for (int j_ = 0; j_ < 2; ++j_) {                                           \
      int S_ = j_ * 256 + tid;                                                 \
      int row_ = S_ >> 2, sl_ = (S_ & 3) ^ ((row_ >> 1) & 3);                  \
      gld16(Bt + (size_t)(n0 + row_) * K + k0_ + (sl_ << 3), Bs[BF] + S_ * 8); \
    }                                                                          \
  } while (0)

  const int ktiles = K >> 5;                     // 32
  GSTAGE(0, 0);
  GSTAGE(1, 1);
  for (int kt = 0; kt < ktiles; ++kt) {
    if (kt + 1 < ktiles) asm volatile("s_waitcnt vmcnt(4)" ::: "memory");  // stage(kt) done
    else                 asm volatile("s_waitcnt vmcnt(0)" ::: "memory");
    __builtin_amdgcn_s_barrier();
    asm volatile("" ::: "memory");
    if (kt + 2 < ktiles) GSTAGE((kt + 2) % 3, kt + 2);

    const bf16* Ac = As[kt % 3];
    const bf16* Bc = Bs[kt % 3];
    bf16x8 af[4], bfr[4];
#pragma unroll
    for (int i = 0; i < 4; i++) {
      int row = wm * 64 + i * 16 + lr;
      int slot = lg ^ ((row >> 1) & 3);
      af[i] = *(const bf16x8*)(Ac + (row << 5) + (slot << 3));
    }
#pragma unroll
    for (int j2 = 0; j2 < 4; j2++) {
      int row = wn * 64 + j2 * 16 + lr;
      int slot = lg ^ ((row >> 1) & 3);
      bfr[j2] = *(const bf16x8*)(Bc + (row << 5) + (slot << 3));
    }
    __builtin_amdgcn_s_setprio(1);
#pragma unroll
    for (int i = 0; i < 4; i++)
#pragma unroll
      for (int j2 = 0; j2 < 4; j2++)
        acc[i][j2] = __builtin_amdgcn_mfma_f32_16x16x32_bf16(af[i], bfr[j2], acc[i][j2], 0, 0, 0);
    __builtin_amdgcn_s_setprio(0);
  }
#undef GSTAGE

  if (EPI == 1) {
#pragma unroll
    for (int i = 0; i < 4; i++) {
      int row = m0 + wm * 64 + i * 16 + lg * 4;
#pragma unroll
      for (int j2 = 0; j2 < 4; j2++) {
        int col = n0 + wn * 64 + j2 * 16 + lr;
        float bv = bias[col];
#pragma unroll
        for (int r = 0; r < 4; r++)
          outF[(size_t)(row + r) * N + col] = acc[i][j2][r] + bv;
      }
    }
  } else {
    const int sect = n0 >> 10;                   // 0=q 1=k 2=v (uniform per block)
#pragma unroll
    for (int i = 0; i < 4; i++) {
      int row = m0 + wm * 64 + i * 16 + lg * 4;
#pragma unroll
      for (int j2 = 0; j2 < 4; j2++) {
        int col = n0 + wn * 64 + j2 * 16 + lr;
        float bv = bias[col];
        int cm = col & 1023;
        int h = cm >> 6, d = cm & 63;
#pragma unroll
        for (int r = 0; r < 4; r++) {
          float v = acc[i][j2][r] + bv;
          int rt = row + r;
          int b = rt >> 11, t = rt & 2047;
          bf16 o = (bf16)v;
          size_t bh = (size_t)(b * H_ + h);
          if (sect == 0)      qb[(bh * T_ + t) * D_ + d] = o;   // [B,H,T,D]
          else if (sect == 1) kb[(bh * T_ + t) * D_ + d] = o;   // [B,H,T,D]
          else                vb[(bh * D_ + d) * T_ + t] = o;   // [B,H,D,T] (V^T)
        }
      }
    }
  }
}

// ---------------- flash attention (32x32 swapped-operand, in-register softmax) ----
// grid: (T/256, B*H); 256 threads = 4 waves, wave w owns 32 q rows.
// bh-per-XCD mapping: all 8 q-blocks of one head on one XCD -> K/V L2-resident
// (8 heads x 512KB = 4MB = L2 per XCD).
// Work-balanced: block handles qblk {NQ-1-p} then {p} -> 34 tiles flat.
// 3-buffer depth-2 prefetch, counted vmcnt(4). T13 defer-max (THR=8).

#if __has_builtin(__builtin_amdgcn_permlane32_swap)
#define PERMSWAP(A, B, LOW, HIW) do {                                           \
    auto _r = __builtin_amdgcn_permlane32_swap((unsigned)(A), (unsigned)(B),    \
                                               false, false);                   \
    __builtin_memcpy(&(LOW), &_r, 4);                                           \
    __builtin_memcpy(&(HIW), (const char*)&_r + 4, 4);                          \
  } while (0)
#else
#define PERMSWAP(A, B, LOW, HIW) do {                                           \
    unsigned _sb = (unsigned)__shfl_xor((int)(B), 32, 64);                      \
    unsigned _sa = (unsigned)__shfl_xor((int)(A), 32, 64);                      \
    (LOW) = hi ? _sb : (A);                                                     \
    (HIW) = hi ? (B) : _sa;                                                     \
  } while (0)
#endif

__global__ __launch_bounds__(256, 4)
void attn_fwd(const bf16* __restrict__ qg, const bf16* __restrict__ kg,
              const bf16* __restrict__ vg, bf16* __restrict__ yb) {
  __shared__ alignas(16) bf16 Ks[3][64 * 64];
  __shared__ alignas(16) bf16 Vs[3][64 * 64];   // V^T tile: [d][k_local]
  const int tid = threadIdx.x;
  const int lane = tid & 63, wid = tid >> 6;
  const int hi = lane >> 5, lq = lane & 31;
  const int xr = (lq & 7) << 4;
  const int NQ = T_ / 128;

  // bh-per-XCD: lbid -> (bh, qpair) with all qpairs of a bh on one XCD
  const int lbid = blockIdx.y * gridDim.x + blockIdx.x;
  const int xcd8 = lbid & 7, idx = lbid >> 3;
  const int bh = xcd8 * 8 + (idx & 7);
  const int qpair = idx >> 3;

  const char* kbase = (const char*)(kg + (size_t)bh * T_ * D_);
  const char* vbase = (const char*)(vg + (size_t)bh * D_ * T_);
  const int b_ = bh >> 4, h = bh & 15;

#define STAGE(BF, TT) do {                                                     \
    _Pragma("unroll")                                                          \
    for (int j_ = 0; j_ < 2; ++j_) {                                           \
      int s_ = j_ * 256 + tid;                                                 \
      int row_ = s_ >> 3;                                                      \
      int scb_ = ((s_ & 7) << 4) ^ ((row_ & 7) << 4);                          \
      gld16(kbase + (size_t)((TT) * 64 + row_) * 128 + scb_,                   \
            (char*)Ks[BF] + s_ * 16);                                          \
      gld16(vbase + (size_t)row_ * (T_ * 2) + (TT) * 128 + scb_,               \
            (char*)Vs[BF] + s_ * 16);                                          \
    }                                                                          \
  } while (0)

  for (int ph = 0; ph < 2; ++ph) {
    const int qblk = ph ? qpair : (NQ - 1 - qpair);
    const int wq0 = qblk * 128 + wid * 32;
    const int qrow = wq0 + lq;
    const int nt = 2 * qblk + 2;

    if (ph) __builtin_amdgcn_s_barrier();   // all waves done reading LDS of ph0
    STAGE(0, 0);
    STAGE(1, 1);

    // Q B-fragments: lane holds q-col = qrow, d = 16s + 8hi + e
    const bf16* qptr = qg + ((size_t)bh * T_ + qrow) * D_ + hi * 8;
    bf16x8 qf[4];
#pragma unroll
    for (int s = 0; s < 4; s++) {
      qf[s] = *(const bf16x8*)(qptr + 16 * s);
      asm volatile("" : "+v"(qf[s]));
    }

    f32x16 o[2] = {};              // O^T: block db rows d=32db+crow, col q=lq
    float mrow = NEG_INF, lrow = 0.f;

    for (int t = 0; t < nt; ++t) {
      if (t + 1 < nt) asm volatile("s_waitcnt vmcnt(4)" ::: "memory");
      else            asm volatile("s_waitcnt vmcnt(0)" ::: "memory");
      __builtin_amdgcn_s_barrier();
      asm volatile("" ::: "memory");
      if (t + 2 < nt) STAGE((t + 2) % 3, t + 2);

      const char* Kc = (const char*)Ks[t % 3];
      const char* Vc = (const char*)Vs[t % 3];

      // S^T[k][q] for this wave's 32 q cols; 2 blocks of 32 k
      f32x16 S[2] = {};
      __builtin_amdgcn_s_setprio(1);
#pragma unroll
      for (int s = 0; s < 4; s++) {
#pragma unroll
        for (int b = 0; b < 2; b++) {
          bf16x8 kf = *(const bf16x8*)(Kc + (b * 32 + lq) * 128 +
                                       ((32 * s + 16 * hi) ^ xr));
          S[b] = __builtin_amdgcn_mfma_f32_32x32x16_bf16(kf, qf[s], S[b], 0, 0, 0);
        }
      }
      __builtin_amdgcn_s_setprio(0);

      // causal mask (raw-score domain)
      if (t >= nt - 2) {
#pragma unroll
        for (int b = 0; b < 2; b++)
#pragma unroll
          for (int r = 0; r < 16; r++) {
            int kgl = t * 64 + b * 32 + (r & 3) + 8 * (r >> 2) + 4 * hi;
            if (kgl > qrow) S[b][r] = NEG_INF;
          }
      }

      // online softmax, in-register; T13 defer-max (THR=8)
      float tm = NEG_INF;
#pragma unroll
      for (int b = 0; b < 2; b++)
#pragma unroll
        for (int r = 0; r < 16; r++) tm = fmaxf(tm, S[b][r]);
      tm = fmaxf(tm, __shfl_xor(tm, 32, 64));
      float tms = 0.125f * tm;

      if (!__all(tms - mrow <= 8.0f)) {
        float mn = fmaxf(mrow, tms);
        float alpha = __expf(mrow - mn);   // exp(-inf)=0 on first tile
        mrow = mn;
        lrow *= alpha;
#pragma unroll
        for (int db = 0; db < 2; db++)
#pragma unroll
          for (int r = 0; r < 16; r++) o[db][r] *= alpha;
      }
      float rs = 0.f;
#pragma unroll
      for (int b = 0; b < 2; b++)
#pragma unroll
        for (int r = 0; r < 16; r++) {
          float e = __expf(fmaf(S[b][r], 0.125f, -mrow));
          S[b][r] = e;
          rs += e;
        }
      rs += __shfl_xor(rs, 32, 64);
      lrow += rs;

      // O^T += V^T * P^T ; P^T B-fragment built via cvt_pk + permlane32_swap
      __builtin_amdgcn_s_setprio(1);
#pragma unroll
      for (int ks = 0; ks < 4; ks++) {
        const int b = ks >> 1, hf = ks & 1;
        unsigned A0 = cvtpk(S[b][8 * hf + 0], S[b][8 * hf + 1]);
        unsigned A1 = cvtpk(S[b][8 * hf + 2], S[b][8 * hf + 3]);
        unsigned B0 = cvtpk(S[b][8 * hf + 4], S[b][8 * hf + 5]);
        unsigned B1 = cvtpk(S[b][8 * hf + 6], S[b][8 * hf + 7]);
        unsigned w0, w1, w2, w3;
        PERMSWAP(A0, B0, w0, w2);
        PERMSWAP(A1, B1, w1, w3);
        u32x4 wv = {w0, w1, w2, w3};
        bf16x8 pf = __builtin_bit_cast(bf16x8, wv);
#pragma unroll
        for (int db = 0; db < 2; db++) {
          bf16x8 vf = *(const bf16x8*)(Vc + (db * 32 + lq) * 128 +
                                       ((32 * ks + 16 * hi) ^ xr));
          o[db] = __builtin_amdgcn_mfma_f32_32x32x16_bf16(vf, pf, o[db], 0, 0, 0);
        }
      }
      __builtin_amdgcn_s_setprio(0);
    }

    // epilogue: O^T lane holds q=qrow col; d = 32db + 8rq + 4hi + rr
    float inv = 1.f / lrow;
    bf16* yrow = yb + ((size_t)(b_ * T_ + qrow)) * C_ + h * 64 + hi * 4;
#pragma unroll
    for (int db = 0; db < 2; db++)
#pragma unroll
      for (int rq = 0; rq < 4; rq++) {
        unsigned w0 = cvtpk(o[db][4 * rq + 0] * inv, o[db][4 * rq + 1] * inv);
        unsigned w1 = cvtpk(o[db][4 * rq + 2] * inv, o[db][4 * rq + 3] * inv);
        u32x2 wv = {w0, w1};
        *(u32x2*)(yrow + db * 32 + rq * 8) = wv;
      }
  }
#undef STAGE
}

// ---------------- launch ----------------

extern "C" void kernel_launch(void* const* d_in, const int* in_sizes, int n_in,
                              void* d_out, int out_size, void* d_ws, size_t ws_size,
                              hipStream_t stream) {
  (void)in_sizes; (void)n_in; (void)out_size; (void)ws_size;
  const float* x      = (const float*)d_in[0];
  const float* w_attn = (const float*)d_in[1];
  const float* b_attn = (const float*)d_in[2];
  const float* w_proj = (const float*)d_in[3];
  const float* b_proj = (const float*)d_in[4];
  float* out = (float*)d_out;

  char* ws = (char*)d_ws;
  bf16* x_bf = (bf16*)ws;  ws += (size_t)BT_ * C_ * 2;      // 16 MB
  bf16* wat  = (bf16*)ws;  ws += (size_t)3 * C_ * C_ * 2;   //  6 MB  [3C][C]
  bf16* wpt  = (bf16*)ws;  ws += (size_t)C_ * C_ * 2;       //  2 MB  [C][C]
  bf16* qbuf = (bf16*)ws;  ws += (size_t)BT_ * C_ * 2;      // 16 MB  [B,H,T,D]
  bf16* kbuf = (bf16*)ws;  ws += (size_t)BT_ * C_ * 2;      // 16 MB  [B,H,T,D]
  bf16* vbuf = (bf16*)ws;  ws += (size_t)BT_ * C_ * 2;      // 16 MB  [B,H,D,T]
  bf16* ybuf = (bf16*)ws;                                    // 16 MB  [B,T,C]

  cast_x<<<(BT_ * C_ / 4) / 256, 256, 0, stream>>>(x, x_bf);
  transpose_cast<<<dim3(3 * C_ / 32, C_ / 32), dim3(32, 8), 0, stream>>>(w_attn, wat, C_, 3 * C_);
  transpose_cast<<<dim3(C_ / 32, C_ / 32), dim3(32, 8), 0, stream>>>(w_proj, wpt, C_, C_);

  gemm_bt<0><<<dim3(3 * C_ / 128, BT_ / 128), 256, 0, stream>>>(
      x_bf, wat, b_attn, nullptr, qbuf, kbuf, vbuf, BT_, 3 * C_, C_);

  attn_fwd<<<dim3(T_ / 256, B_ * H_), 256, 0, stream>>>(qbuf, kbuf, vbuf, ybuf);

  gemm_bt<1><<<dim3(C_ / 128, BT_ / 128), 256, 0, stream>>>(
      ybuf, wpt, b_proj, out, nullptr, nullptr, nullptr, BT_, C_, C_);
}